// Round 10
// baseline (234.288 us; speedup 1.0000x reference)
//
#include <hip/hip_runtime.h>
#include <math.h>

// GCN conv: out = D^{-1/2} (A+I) D^{-1/2} (x W) + b
// d_in[0]=x [100000,128] f32, d_in[1]=edge_index [2,1600000] int32,
// d_in[2]=W1 [128,128] f32, d_in[3]=b1 [128] f32 ; out [100000,128] f32

#define N_NODES 100000
#define N_EDGES 1600000
#define NF 128
#define LDW 136       // padded LDS row stride (bf16 elems)

#define BSHIFT 7                      // 128 nodes per bucket
#define BNODES 128
#define NBUCK 782                     // ceil(100000/128)
#define ECAP 2432                     // bucket cap (mean 2046 + 8.6 sigma)
#define HCAP 1536                     // half-bucket slot capacity (mean 1023)
#define CHUNK 16384                   // edges per binning block (4x coarser)
#define NCHUNK 98                     // ceil(1600000/16384)
#define GEMM_BLOCKS 1563              // ceil(100000/64)

typedef short bf16x8 __attribute__((ext_vector_type(8)));
typedef float f32x4  __attribute__((ext_vector_type(4)));
typedef unsigned short u16;

__device__ inline u16 f2bf(float f) {
    unsigned int u = __float_as_uint(f);
    return (u16)((u + 0x7fffu + ((u >> 16) & 1u)) >> 16);  // RN-even
}

// biased-uint8 unpack: compiles to v_cvt_f32_ubyte0..3 (1 op per value)
__device__ inline f32x4 unpk4u(unsigned int u) {
    f32x4 r;
    r[0] = (float)(u & 0xffu);
    r[1] = (float)((u >> 8) & 0xffu);
    r[2] = (float)((u >> 16) & 0xffu);
    r[3] = (float)(u >> 24);
    return r;
}

// ---------------------------------------------------------------------------
// prep: W [128,128] f32 -> PADDED bf16 W^T image (LDS mirror, 34816 B);
//       block 0 zeroes bcur. 16 blocks.   (proven)
// ---------------------------------------------------------------------------
__global__ __launch_bounds__(256) void prep_kernel(const float* __restrict__ W,
                                                   u16* __restrict__ Wimg,
                                                   int* __restrict__ bcur) {
    const int t = threadIdx.x;
    if (blockIdx.x == 0)
        for (int b = t; b < NBUCK; b += 256) bcur[b] = 0;
    for (int idx = blockIdx.x * 256 + t; idx < NF * NF; idx += 16 * 256) {
        int n = idx >> 7, k = idx & 127;
        Wimg[n * LDW + k] = f2bf(W[k * NF + n]);
    }
}

// ---------------------------------------------------------------------------
// F1: binning blocks FIRST [0,NCHUNK); GEMM blocks after.
//     Binning (NEW granularity): 98 blocks x 16384 edges, NO LDS edge
//     staging (ei re-read from L2 at scatter). Per-bucket reservation
//     atomics drop 306k -> 76k (4x less same-address contention) and the
//     98 blocks hide fully under the 1563 gemm blocks.
//     GEMM: identical to the round-5-proven version.
// ---------------------------------------------------------------------------
__global__ __launch_bounds__(256, 4) void fused1_kernel(const float* __restrict__ x,
                                                        const u16* __restrict__ Wimg,
                                                        signed char* __restrict__ h8,
                                                        float* __restrict__ rscale,
                                                        const int* __restrict__ ei,
                                                        int* __restrict__ bcur,
                                                        unsigned int* __restrict__ ebuf) {
    __shared__ __align__(16) char smem[34816];
    const int t = threadIdx.x;

    if (blockIdx.x < NCHUNK) {
        // ---------------- binning part (runs first, overlaps gemm) ---------
        int* cnt = (int*)smem;                   // 3128 B
        int* cur = (int*)(smem + 3200);          // 3128 B
        const int c = blockIdx.x;
        for (int b = t; b < NBUCK; b += 256) cnt[b] = 0;
        __syncthreads();
        const int e0 = c * CHUNK;
        #pragma unroll 8
        for (int it = 0; it < CHUNK / 256; ++it) {
            int e = e0 + it * 256 + t;
            if (e < N_EDGES) atomicAdd(&cnt[ei[N_EDGES + e] >> BSHIFT], 1);
        }
        __syncthreads();
        for (int b = t; b < NBUCK; b += 256) {
            int v = cnt[b];
            cur[b] = b * ECAP + (v ? atomicAdd(&bcur[b], v) : 0);
        }
        __syncthreads();
        #pragma unroll 8
        for (int it = 0; it < CHUNK / 256; ++it) {
            int e = e0 + it * 256 + t;
            if (e < N_EDGES) {
                int d = ei[N_EDGES + e];           // L2 hit (2nd pass)
                int pos = atomicAdd(&cur[d >> BSHIFT], 1);
                ebuf[pos] = ((unsigned)(d & (BNODES - 1)) << 17)
                          | (unsigned)ei[e];
            }
        }
        return;
    }

    // ---------------- gemm part (round-5 proven) ----------------
    const int gb = blockIdx.x - NCHUNK;
    const int lane = t & 63;
    const int w = t >> 6;
    const int quad = lane >> 4;
    const int m = lane & 15;
    const int rowbase = gb * 64;
    const int r0 = w * 16;
    const int arow = rowbase + r0 + m;          // this lane's A row
    const bool rv = arow < N_NODES;
    const float4* x4 = (const float4*)x;

    u16* Wt = (u16*)smem;                        // 34816 B padded W^T
    for (int idx = t; idx < (NF * LDW * 2) / 16; idx += 256)
        ((uint4*)Wt)[idx] = ((const uint4*)Wimg)[idx];

    // prefetch all A data (8 float4) before touching LDS results
    float4 xr[8];
    #pragma unroll
    for (int kt = 0; kt < 4; ++kt) {
        if (rv) {
            xr[2 * kt]     = x4[arow * 32 + kt * 8 + quad * 2];
            xr[2 * kt + 1] = x4[arow * 32 + kt * 8 + quad * 2 + 1];
        } else {
            xr[2 * kt] = make_float4(0.f, 0.f, 0.f, 0.f);
            xr[2 * kt + 1] = make_float4(0.f, 0.f, 0.f, 0.f);
        }
    }
    __syncthreads();

    f32x4 acc[8];
    #pragma unroll
    for (int nt = 0; nt < 8; ++nt) acc[nt] = (f32x4){0.f, 0.f, 0.f, 0.f};

    #pragma unroll
    for (int kt = 0; kt < 4; ++kt) {
        bf16x8 a;
        a[0] = (short)f2bf(xr[2 * kt].x);     a[1] = (short)f2bf(xr[2 * kt].y);
        a[2] = (short)f2bf(xr[2 * kt].z);     a[3] = (short)f2bf(xr[2 * kt].w);
        a[4] = (short)f2bf(xr[2 * kt + 1].x); a[5] = (short)f2bf(xr[2 * kt + 1].y);
        a[6] = (short)f2bf(xr[2 * kt + 1].z); a[7] = (short)f2bf(xr[2 * kt + 1].w);
        #pragma unroll
        for (int nt = 0; nt < 8; ++nt) {
            bf16x8 bb = *(const bf16x8*)&Wt[(nt * 16 + m) * LDW + kt * 32 + quad * 8];
            acc[nt] = __builtin_amdgcn_mfma_f32_16x16x32_bf16(a, bb, acc[nt], 0, 0, 0);
        }
    }

    float rmax[4];
    #pragma unroll
    for (int r = 0; r < 4; ++r) {
        float mx = 0.f;
        #pragma unroll
        for (int nt = 0; nt < 8; ++nt) mx = fmaxf(mx, fabsf(acc[nt][r]));
        #pragma unroll
        for (int off = 1; off < 16; off <<= 1) mx = fmaxf(mx, __shfl_xor(mx, off));
        rmax[r] = fmaxf(mx, 1e-20f);
    }

    __syncthreads();     // all Wt reads complete -> safe to alias
    char* xs8 = smem;    // 64 rows x 144B stride = 9216 B bounce
    #pragma unroll
    for (int r = 0; r < 4; ++r) {
        const float inv = 127.f / rmax[r];
        const int row = r0 + quad * 4 + r;
        #pragma unroll
        for (int nt = 0; nt < 8; ++nt) {
            int q = __float2int_rn(acc[nt][r] * inv) + 128;   // biased
            xs8[row * 144 + nt * 16 + m] = (char)q;
        }
        if (m == 0) {
            int grow = rowbase + row;
            if (grow < N_NODES) rscale[grow] = rmax[r] * (1.f / 127.f);
        }
    }
    __syncthreads();

    for (int it = 0; it < 2; ++it) {
        int linear = it * 256 + t;
        int row = linear >> 3, seg = linear & 7;
        int grow = rowbase + row;
        if (grow < N_NODES) {
            uint4 v = *(const uint4*)&xs8[row * 144 + seg * 16];
            ((uint4*)h8)[grow * 8 + seg] = v;
        }
    }
}

// ---------------------------------------------------------------------------
// comboK: per bucket, count per-node degree from the bucket run (LDS
//         atomics), write combo = rsqrt(deg+1)*rscale.   (proven)
// ---------------------------------------------------------------------------
__global__ __launch_bounds__(256) void comboK_kernel(const unsigned int* __restrict__ ebuf,
                                                     const int* __restrict__ bcur,
                                                     const float* __restrict__ rscale,
                                                     float* __restrict__ combo) {
    __shared__ int lcnt[BNODES];
    const int t = threadIdx.x, bkt = blockIdx.x;
    if (t < BNODES) lcnt[t] = 0;
    __syncthreads();
    const int cnt = min(bcur[bkt], ECAP);
    for (int e = t; e < cnt; e += 256)
        atomicAdd(&lcnt[ebuf[bkt * ECAP + e] >> 17], 1);
    __syncthreads();
    if (t < BNODES) {
        int n = (bkt << BSHIFT) + t;
        if (n < N_NODES)
            combo[n] = rsqrtf((float)lcnt[t] + 1.0f) * rscale[n];
    }
}

// ---------------------------------------------------------------------------
// aggB: one block per HALF bucket (64 nodes, 1564 blocks).  (round-9 proven)
// count -> scan -> scatter {src,w} into LDS -> broadcast-read gather,
// 2 nodes per wave, no per-edge shfl, no cross-lane reduce.
// ---------------------------------------------------------------------------
__global__ __launch_bounds__(256) void aggB_kernel(const unsigned int* __restrict__ ebuf,
                                                   const int* __restrict__ bcur,
                                                   const float* __restrict__ rscale,
                                                   const float* __restrict__ combo,
                                                   const signed char* __restrict__ h8,
                                                   const float* __restrict__ b,
                                                   float* __restrict__ out) {
    __shared__ __align__(8) uint2 lsw[HCAP + 4];
    __shared__ int lcnt[64];
    __shared__ int lbase[64];
    __shared__ int lcur[64];
    const int t = threadIdx.x;
    const int bkt = blockIdx.x >> 1;
    const int hb  = blockIdx.x & 1;
    const int n0  = (bkt << BSHIFT) + hb * 64;   // first node of this half
    const unsigned lo = (unsigned)(hb * 64), hi = lo + 64u;
    const int cnt = min(bcur[bkt], ECAP);
    const int rbase = bkt * ECAP;

    if (t < 64) lcnt[t] = 0;
    __syncthreads();
    for (int e = t; e < cnt; e += 256) {
        unsigned p = ebuf[rbase + e];
        unsigned ld = p >> 17;
        if (ld >= lo && ld < hi) atomicAdd(&lcnt[ld - lo], 1);
    }
    __syncthreads();
    if (t < 64) {                      // wave-0 shfl scan of 64 counts
        int v = lcnt[t];
        int s = v;
        #pragma unroll
        for (int off = 1; off < 64; off <<= 1) {
            int u = __shfl_up(s, off);
            if (t >= off) s += u;
        }
        lbase[t] = s - v;
        lcur[t]  = s - v;
    }
    __syncthreads();
    for (int e = t; e < cnt; e += 256) {
        unsigned p = ebuf[rbase + e];
        unsigned ld = p >> 17;
        if (ld >= lo && ld < hi) {
            unsigned src = p & 0x1ffffu;
            float wv = combo[src];               // edge-parallel gather
            int pos = atomicAdd(&lcur[ld - lo], 1);
            if (pos < HCAP) lsw[pos] = make_uint2(src, __float_as_uint(wv));
        }
    }
    __syncthreads();

    // ---------------- gather: 4 waves x 8 node-pairs ----------------
    const int wave = t >> 6;
    const int lane = t & 63;
    const int half = lane >> 5;
    const int col  = lane & 31;
    const unsigned int* h4 = (const unsigned int*)h8;
    const float4 bb = ((const float4*)b)[col];

    for (int pp = 0; pp < 8; ++pp) {
        const int li = wave * 16 + pp * 2 + half;   // this half's node
        const int i  = n0 + li;
        const bool valid = i < N_NODES;
        const int deg  = valid ? lcnt[li] : 0;
        const int base = valid ? lbase[li] : 0;
        const int m    = min(deg, HCAP - base);     // defensive clamp

        f32x4 a0 = {0.f,0.f,0.f,0.f}, a1 = {0.f,0.f,0.f,0.f};
        f32x4 a2 = {0.f,0.f,0.f,0.f}, a3 = {0.f,0.f,0.f,0.f};
        float ws = 0.f;
        for (int j = 0; j < m; j += 4) {
            uint2 sw0 = lsw[base + j];              // broadcast b64 reads
            uint2 sw1 = lsw[base + j + 1];
            uint2 sw2 = lsw[base + j + 2];
            uint2 sw3 = lsw[base + j + 3];
            bool o1 = (j + 1) < m, o2 = (j + 2) < m, o3 = (j + 3) < m;
            unsigned s0 = sw0.x;
            unsigned s1 = o1 ? sw1.x : 0u;
            unsigned s2 = o2 ? sw2.x : 0u;
            unsigned s3 = o3 ? sw3.x : 0u;
            float w0 = __uint_as_float(sw0.y);
            float w1 = o1 ? __uint_as_float(sw1.y) : 0.f;
            float w2 = o2 ? __uint_as_float(sw2.y) : 0.f;
            float w3 = o3 ? __uint_as_float(sw3.y) : 0.f;
            unsigned u0 = h4[s0 * 32 + col];
            unsigned u1 = h4[s1 * 32 + col];
            unsigned u2 = h4[s2 * 32 + col];
            unsigned u3 = h4[s3 * 32 + col];
            ws += (w0 + w1) + (w2 + w3);
            a0 += unpk4u(u0) * w0;
            a1 += unpk4u(u1) * w1;
            a2 += unpk4u(u2) * w2;
            a3 += unpk4u(u3) * w3;
        }
        f32x4 acc = (a0 + a1) + (a2 + a3);

        if (valid) {
            const float di = rsqrtf((float)deg + 1.0f);
            const float ci = di * rscale[i];
            unsigned uv = h4[i * 32 + col];
            f32x4 hv = unpk4u(uv);
            const float corr = 128.f * (ws + ci);   // bias corr (incl. self)
            float4 o4;
            o4.x = bb.x + di * (acc[0] + ci * hv[0] - corr);
            o4.y = bb.y + di * (acc[1] + ci * hv[1] - corr);
            o4.z = bb.z + di * (acc[2] + ci * hv[2] - corr);
            o4.w = bb.w + di * (acc[3] + ci * hv[3] - corr);
            ((float4*)out)[i * 32 + col] = o4;
        }
    }
}

// ---------------------------------------------------------------------------
extern "C" void kernel_launch(void* const* d_in, const int* in_sizes, int n_in,
                              void* d_out, int out_size, void* d_ws, size_t ws_size,
                              hipStream_t stream) {
    const float* x  = (const float*)d_in[0];
    const int*   ei = (const int*)d_in[1];
    const float* W  = (const float*)d_in[2];
    const float* b  = (const float*)d_in[3];
    float* out = (float*)d_out;

    // ws layout (4B-unit offsets):
    // h8 [0..3.2M) | rscale 3.3M | combo 3.45M | bcur 4.13M |
    // Wimg 4.14M (34.8KB) | ebuf [4.3M .. 4.3M+782*2432=6.20M)
    signed char* h8 = (signed char*)d_ws;
    float* rscale = (float*)d_ws + 3300000;
    float* combo  = (float*)d_ws + 3450000;
    int*   bcur   = (int*)d_ws + 4130000;
    u16*   Wimg   = (u16*)((int*)d_ws + 4140000);
    unsigned int* ebuf = (unsigned int*)d_ws + 4300000;

    prep_kernel<<<16, 256, 0, stream>>>(W, Wimg, bcur);
    fused1_kernel<<<NCHUNK + GEMM_BLOCKS, 256, 0, stream>>>(x, Wimg, h8, rscale,
                                                            ei, bcur, ebuf);
    comboK_kernel<<<NBUCK, 256, 0, stream>>>(ebuf, bcur, rscale, combo);
    aggB_kernel<<<NBUCK * 2, 256, 0, stream>>>(ebuf, bcur, rscale, combo, h8, b, out);
}

// Round 11
// 185.559 us; speedup vs baseline: 1.2626x; 1.2626x over previous
//
#include <hip/hip_runtime.h>
#include <math.h>

// GCN conv: out = D^{-1/2} (A+I) D^{-1/2} (x W) + b
// d_in[0]=x [100000,128] f32, d_in[1]=edge_index [2,1600000] int32,
// d_in[2]=W1 [128,128] f32, d_in[3]=b1 [128] f32 ; out [100000,128] f32

#define N_NODES 100000
#define N_EDGES 1600000
#define NF 128
#define LDW 136       // padded LDS row stride (bf16 elems)

#define BSHIFT 7                      // 128 nodes per bucket
#define BNODES 128
#define NBUCK 782                     // ceil(100000/128)
#define ECAP 2432                     // bucket cap (mean 2046 + 8.6 sigma)
#define HCAP 1536                     // half-bucket slot capacity (mean 1023)
#define CHUNK 4096                    // edges per binning block (R9 proven)
#define NCHUNK 391                    // ceil(1600000/4096)
#define GEMM_BLOCKS 782               // ceil(100000/128) -- 128 rows/block

typedef short bf16x8 __attribute__((ext_vector_type(8)));
typedef float f32x4  __attribute__((ext_vector_type(4)));
typedef unsigned short u16;

__device__ inline u16 f2bf(float f) {
    unsigned int u = __float_as_uint(f);
    return (u16)((u + 0x7fffu + ((u >> 16) & 1u)) >> 16);  // RN-even
}

// biased-uint8 unpack: compiles to v_cvt_f32_ubyte0..3 (1 op per value)
__device__ inline f32x4 unpk4u(unsigned int u) {
    f32x4 r;
    r[0] = (float)(u & 0xffu);
    r[1] = (float)((u >> 8) & 0xffu);
    r[2] = (float)((u >> 16) & 0xffu);
    r[3] = (float)(u >> 24);
    return r;
}

// ---------------------------------------------------------------------------
// prep: W [128,128] f32 -> PADDED bf16 W^T image (LDS mirror, 34816 B);
//       block 0 zeroes bcur. 16 blocks.   (proven)
// ---------------------------------------------------------------------------
__global__ __launch_bounds__(256) void prep_kernel(const float* __restrict__ W,
                                                   u16* __restrict__ Wimg,
                                                   int* __restrict__ bcur) {
    const int t = threadIdx.x;
    if (blockIdx.x == 0)
        for (int b = t; b < NBUCK; b += 256) bcur[b] = 0;
    for (int idx = blockIdx.x * 256 + t; idx < NF * NF; idx += 16 * 256) {
        int n = idx >> 7, k = idx & 127;
        Wimg[n * LDW + k] = f2bf(W[k * NF + n]);
    }
}

// ---------------------------------------------------------------------------
// F1: binning blocks FIRST [0,NCHUNK) (R9-proven: 391 blocks, LDS-staged).
//     GEMM (NEW): 128 rows/block, 782 blocks. Each wave owns two 16-row
//     tiles; tile-B A-frags prefetch under tile-A MFMAs. Halves W staging
//     and barrier count per row. h8 stored BIASED (+128).
// ---------------------------------------------------------------------------
__global__ __launch_bounds__(256, 3) void fused1_kernel(const float* __restrict__ x,
                                                        const u16* __restrict__ Wimg,
                                                        signed char* __restrict__ h8,
                                                        float* __restrict__ rscale,
                                                        const int* __restrict__ ei,
                                                        int* __restrict__ bcur,
                                                        unsigned int* __restrict__ ebuf) {
    __shared__ __align__(16) char smem[39040];
    const int t = threadIdx.x;

    if (blockIdx.x < NCHUNK) {
        // ---------------- binning part (R9-proven) ----------------
        unsigned int* ed = (unsigned int*)smem;            // 16384 B
        unsigned int* es = (unsigned int*)(smem + 16384);  // 16384 B
        int* cnt = (int*)(smem + 32768);                   // 3128 B
        int* cur = (int*)(smem + 32768 + 3136);            // 3128 B
        const int c = blockIdx.x;
        for (int b = t; b < NBUCK; b += 256) cnt[b] = 0;
        const int e0 = c * CHUNK;
        #pragma unroll 4
        for (int it = 0; it < CHUNK / 256; ++it) {
            int k = it * 256 + t, e = e0 + k;
            if (e < N_EDGES) {
                ed[k] = (unsigned int)ei[N_EDGES + e];
                es[k] = (unsigned int)ei[e];
            } else ed[k] = 0xFFFFFFFFu;
        }
        __syncthreads();
        #pragma unroll 4
        for (int it = 0; it < CHUNK / 256; ++it) {
            unsigned int d = ed[it * 256 + t];
            if (d != 0xFFFFFFFFu) atomicAdd(&cnt[d >> BSHIFT], 1);
        }
        __syncthreads();
        for (int b = t; b < NBUCK; b += 256) {
            int v = cnt[b];
            cur[b] = b * ECAP + (v ? atomicAdd(&bcur[b], v) : 0);
        }
        __syncthreads();
        #pragma unroll 4
        for (int it = 0; it < CHUNK / 256; ++it) {
            int k = it * 256 + t;
            unsigned int d = ed[k];
            if (d != 0xFFFFFFFFu) {
                int pos = atomicAdd(&cur[d >> BSHIFT], 1);
                ebuf[pos] = ((d & (BNODES - 1u)) << 17) | es[k];
            }
        }
        return;
    }

    // ---------------- gemm part: 128 rows, dual 16-row tiles per wave ------
    const int gb = blockIdx.x - NCHUNK;
    const int lane = t & 63;
    const int w = t >> 6;
    const int quad = lane >> 4;
    const int m = lane & 15;
    const int rowbase = gb * 128;
    const int wbase = w * 32;                    // wave's 32-row span
    const int arowA = rowbase + wbase + m;       // tile A row
    const int arowB = arowA + 16;                // tile B row
    const bool rvA = arowA < N_NODES;
    const bool rvB = arowB < N_NODES;
    const float4* x4 = (const float4*)x;

    u16* Wt = (u16*)smem;                        // 34816 B padded W^T
    for (int idx = t; idx < (NF * LDW * 2) / 16; idx += 256)
        ((uint4*)Wt)[idx] = ((const uint4*)Wimg)[idx];

    // prefetch tile-A data (8 float4) behind the W staging
    float4 xrA[8];
    #pragma unroll
    for (int kt = 0; kt < 4; ++kt) {
        if (rvA) {
            xrA[2 * kt]     = x4[arowA * 32 + kt * 8 + quad * 2];
            xrA[2 * kt + 1] = x4[arowA * 32 + kt * 8 + quad * 2 + 1];
        } else {
            xrA[2 * kt] = make_float4(0.f, 0.f, 0.f, 0.f);
            xrA[2 * kt + 1] = make_float4(0.f, 0.f, 0.f, 0.f);
        }
    }
    __syncthreads();

    // issue tile-B prefetch now; it completes under tile-A MFMAs
    float4 xrB[8];
    #pragma unroll
    for (int kt = 0; kt < 4; ++kt) {
        if (rvB) {
            xrB[2 * kt]     = x4[arowB * 32 + kt * 8 + quad * 2];
            xrB[2 * kt + 1] = x4[arowB * 32 + kt * 8 + quad * 2 + 1];
        } else {
            xrB[2 * kt] = make_float4(0.f, 0.f, 0.f, 0.f);
            xrB[2 * kt + 1] = make_float4(0.f, 0.f, 0.f, 0.f);
        }
    }

    f32x4 accA[8], accB[8];
    #pragma unroll
    for (int nt = 0; nt < 8; ++nt) {
        accA[nt] = (f32x4){0.f, 0.f, 0.f, 0.f};
        accB[nt] = (f32x4){0.f, 0.f, 0.f, 0.f};
    }

    #pragma unroll
    for (int kt = 0; kt < 4; ++kt) {
        bf16x8 a;
        a[0] = (short)f2bf(xrA[2 * kt].x);     a[1] = (short)f2bf(xrA[2 * kt].y);
        a[2] = (short)f2bf(xrA[2 * kt].z);     a[3] = (short)f2bf(xrA[2 * kt].w);
        a[4] = (short)f2bf(xrA[2 * kt + 1].x); a[5] = (short)f2bf(xrA[2 * kt + 1].y);
        a[6] = (short)f2bf(xrA[2 * kt + 1].z); a[7] = (short)f2bf(xrA[2 * kt + 1].w);
        #pragma unroll
        for (int nt = 0; nt < 8; ++nt) {
            bf16x8 bb = *(const bf16x8*)&Wt[(nt * 16 + m) * LDW + kt * 32 + quad * 8];
            accA[nt] = __builtin_amdgcn_mfma_f32_16x16x32_bf16(a, bb, accA[nt], 0, 0, 0);
        }
    }
    #pragma unroll
    for (int kt = 0; kt < 4; ++kt) {
        bf16x8 a;
        a[0] = (short)f2bf(xrB[2 * kt].x);     a[1] = (short)f2bf(xrB[2 * kt].y);
        a[2] = (short)f2bf(xrB[2 * kt].z);     a[3] = (short)f2bf(xrB[2 * kt].w);
        a[4] = (short)f2bf(xrB[2 * kt + 1].x); a[5] = (short)f2bf(xrB[2 * kt + 1].y);
        a[6] = (short)f2bf(xrB[2 * kt + 1].z); a[7] = (short)f2bf(xrB[2 * kt + 1].w);
        #pragma unroll
        for (int nt = 0; nt < 8; ++nt) {
            bf16x8 bb = *(const bf16x8*)&Wt[(nt * 16 + m) * LDW + kt * 32 + quad * 8];
            accB[nt] = __builtin_amdgcn_mfma_f32_16x16x32_bf16(a, bb, accB[nt], 0, 0, 0);
        }
    }

    float rmaxA[4], rmaxB[4];
    #pragma unroll
    for (int r = 0; r < 4; ++r) {
        float mxA = 0.f, mxB = 0.f;
        #pragma unroll
        for (int nt = 0; nt < 8; ++nt) {
            mxA = fmaxf(mxA, fabsf(accA[nt][r]));
            mxB = fmaxf(mxB, fabsf(accB[nt][r]));
        }
        #pragma unroll
        for (int off = 1; off < 16; off <<= 1) {
            mxA = fmaxf(mxA, __shfl_xor(mxA, off));
            mxB = fmaxf(mxB, __shfl_xor(mxB, off));
        }
        rmaxA[r] = fmaxf(mxA, 1e-20f);
        rmaxB[r] = fmaxf(mxB, 1e-20f);
    }

    __syncthreads();     // all Wt reads complete -> safe to alias
    char* xs8 = smem;    // 128 rows x 144B stride = 18432 B bounce
    #pragma unroll
    for (int r = 0; r < 4; ++r) {
        const float invA = 127.f / rmaxA[r];
        const float invB = 127.f / rmaxB[r];
        const int rowA = wbase + quad * 4 + r;
        const int rowB = rowA + 16;
        #pragma unroll
        for (int nt = 0; nt < 8; ++nt) {
            int qA = __float2int_rn(accA[nt][r] * invA) + 128;   // biased
            int qB = __float2int_rn(accB[nt][r] * invB) + 128;
            xs8[rowA * 144 + nt * 16 + m] = (char)qA;
            xs8[rowB * 144 + nt * 16 + m] = (char)qB;
        }
        if (m == 0) {
            int gA = rowbase + rowA, gB = rowbase + rowB;
            if (gA < N_NODES) rscale[gA] = rmaxA[r] * (1.f / 127.f);
            if (gB < N_NODES) rscale[gB] = rmaxB[r] * (1.f / 127.f);
        }
    }
    __syncthreads();

    for (int it = 0; it < 4; ++it) {
        int linear = it * 256 + t;
        int row = linear >> 3, seg = linear & 7;
        int grow = rowbase + row;
        if (grow < N_NODES) {
            uint4 v = *(const uint4*)&xs8[row * 144 + seg * 16];
            ((uint4*)h8)[grow * 8 + seg] = v;
        }
    }
}

// ---------------------------------------------------------------------------
// comboK: per bucket, count per-node degree from the bucket run (LDS
//         atomics), write combo = rsqrt(deg+1)*rscale.   (proven)
// ---------------------------------------------------------------------------
__global__ __launch_bounds__(256) void comboK_kernel(const unsigned int* __restrict__ ebuf,
                                                     const int* __restrict__ bcur,
                                                     const float* __restrict__ rscale,
                                                     float* __restrict__ combo) {
    __shared__ int lcnt[BNODES];
    const int t = threadIdx.x, bkt = blockIdx.x;
    if (t < BNODES) lcnt[t] = 0;
    __syncthreads();
    const int cnt = min(bcur[bkt], ECAP);
    for (int e = t; e < cnt; e += 256)
        atomicAdd(&lcnt[ebuf[bkt * ECAP + e] >> 17], 1);
    __syncthreads();
    if (t < BNODES) {
        int n = (bkt << BSHIFT) + t;
        if (n < N_NODES)
            combo[n] = rsqrtf((float)lcnt[t] + 1.0f) * rscale[n];
    }
}

// ---------------------------------------------------------------------------
// aggB: one block per HALF bucket (64 nodes, 1564 blocks).  (R9-proven
// skeleton; inner gather loop unrolled 4 -> 8 for deeper MLP.)
// ---------------------------------------------------------------------------
__global__ __launch_bounds__(256) void aggB_kernel(const unsigned int* __restrict__ ebuf,
                                                   const int* __restrict__ bcur,
                                                   const float* __restrict__ rscale,
                                                   const float* __restrict__ combo,
                                                   const signed char* __restrict__ h8,
                                                   const float* __restrict__ b,
                                                   float* __restrict__ out) {
    __shared__ __align__(8) uint2 lsw[HCAP + 8];
    __shared__ int lcnt[64];
    __shared__ int lbase[64];
    __shared__ int lcur[64];
    const int t = threadIdx.x;
    const int bkt = blockIdx.x >> 1;
    const int hb  = blockIdx.x & 1;
    const int n0  = (bkt << BSHIFT) + hb * 64;   // first node of this half
    const unsigned lo = (unsigned)(hb * 64), hi = lo + 64u;
    const int cnt = min(bcur[bkt], ECAP);
    const int rbase = bkt * ECAP;

    if (t < 64) lcnt[t] = 0;
    __syncthreads();
    for (int e = t; e < cnt; e += 256) {
        unsigned p = ebuf[rbase + e];
        unsigned ld = p >> 17;
        if (ld >= lo && ld < hi) atomicAdd(&lcnt[ld - lo], 1);
    }
    __syncthreads();
    if (t < 64) {                      // wave-0 shfl scan of 64 counts
        int v = lcnt[t];
        int s = v;
        #pragma unroll
        for (int off = 1; off < 64; off <<= 1) {
            int u = __shfl_up(s, off);
            if (t >= off) s += u;
        }
        lbase[t] = s - v;
        lcur[t]  = s - v;
    }
    __syncthreads();
    for (int e = t; e < cnt; e += 256) {
        unsigned p = ebuf[rbase + e];
        unsigned ld = p >> 17;
        if (ld >= lo && ld < hi) {
            unsigned src = p & 0x1ffffu;
            float wv = combo[src];               // edge-parallel gather
            int pos = atomicAdd(&lcur[ld - lo], 1);
            if (pos < HCAP) lsw[pos] = make_uint2(src, __float_as_uint(wv));
        }
    }
    __syncthreads();

    // ---------------- gather: 4 waves x 8 node-pairs ----------------
    const int wave = t >> 6;
    const int lane = t & 63;
    const int half = lane >> 5;
    const int col  = lane & 31;
    const unsigned int* h4 = (const unsigned int*)h8;
    const float4 bb = ((const float4*)b)[col];

    for (int pp = 0; pp < 8; ++pp) {
        const int li = wave * 16 + pp * 2 + half;   // this half's node
        const int i  = n0 + li;
        const bool valid = i < N_NODES;
        const int deg  = valid ? lcnt[li] : 0;
        const int base = valid ? lbase[li] : 0;
        const int m    = min(deg, HCAP - base);     // defensive clamp

        f32x4 a0 = {0.f,0.f,0.f,0.f}, a1 = {0.f,0.f,0.f,0.f};
        f32x4 a2 = {0.f,0.f,0.f,0.f}, a3 = {0.f,0.f,0.f,0.f};
        float ws = 0.f;
        for (int j = 0; j < m; j += 8) {
            uint2 sw0 = lsw[base + j];              // broadcast b64 reads
            uint2 sw1 = lsw[base + j + 1];
            uint2 sw2 = lsw[base + j + 2];
            uint2 sw3 = lsw[base + j + 3];
            uint2 sw4 = lsw[base + j + 4];
            uint2 sw5 = lsw[base + j + 5];
            uint2 sw6 = lsw[base + j + 6];
            uint2 sw7 = lsw[base + j + 7];
            bool o1 = (j + 1) < m, o2 = (j + 2) < m, o3 = (j + 3) < m;
            bool o4 = (j + 4) < m, o5 = (j + 5) < m, o6 = (j + 6) < m;
            bool o7 = (j + 7) < m;
            unsigned s0 = sw0.x;
            unsigned s1 = o1 ? sw1.x : 0u;
            unsigned s2 = o2 ? sw2.x : 0u;
            unsigned s3 = o3 ? sw3.x : 0u;
            unsigned s4 = o4 ? sw4.x : 0u;
            unsigned s5 = o5 ? sw5.x : 0u;
            unsigned s6 = o6 ? sw6.x : 0u;
            unsigned s7 = o7 ? sw7.x : 0u;
            float w0 = __uint_as_float(sw0.y);
            float w1 = o1 ? __uint_as_float(sw1.y) : 0.f;
            float w2 = o2 ? __uint_as_float(sw2.y) : 0.f;
            float w3 = o3 ? __uint_as_float(sw3.y) : 0.f;
            float w4 = o4 ? __uint_as_float(sw4.y) : 0.f;
            float w5 = o5 ? __uint_as_float(sw5.y) : 0.f;
            float w6 = o6 ? __uint_as_float(sw6.y) : 0.f;
            float w7 = o7 ? __uint_as_float(sw7.y) : 0.f;
            unsigned u0 = h4[s0 * 32 + col];
            unsigned u1 = h4[s1 * 32 + col];
            unsigned u2 = h4[s2 * 32 + col];
            unsigned u3 = h4[s3 * 32 + col];
            unsigned u4 = h4[s4 * 32 + col];
            unsigned u5 = h4[s5 * 32 + col];
            unsigned u6 = h4[s6 * 32 + col];
            unsigned u7 = h4[s7 * 32 + col];
            ws += (w0 + w1) + (w2 + w3) + (w4 + w5) + (w6 + w7);
            a0 += unpk4u(u0) * w0;
            a1 += unpk4u(u1) * w1;
            a2 += unpk4u(u2) * w2;
            a3 += unpk4u(u3) * w3;
            a0 += unpk4u(u4) * w4;
            a1 += unpk4u(u5) * w5;
            a2 += unpk4u(u6) * w6;
            a3 += unpk4u(u7) * w7;
        }
        f32x4 acc = (a0 + a1) + (a2 + a3);

        if (valid) {
            const float di = rsqrtf((float)deg + 1.0f);
            const float ci = di * rscale[i];
            unsigned uv = h4[i * 32 + col];
            f32x4 hv = unpk4u(uv);
            const float corr = 128.f * (ws + ci);   // bias corr (incl. self)
            float4 o4v;
            o4v.x = bb.x + di * (acc[0] + ci * hv[0] - corr);
            o4v.y = bb.y + di * (acc[1] + ci * hv[1] - corr);
            o4v.z = bb.z + di * (acc[2] + ci * hv[2] - corr);
            o4v.w = bb.w + di * (acc[3] + ci * hv[3] - corr);
            ((float4*)out)[i * 32 + col] = o4v;
        }
    }
}

// ---------------------------------------------------------------------------
extern "C" void kernel_launch(void* const* d_in, const int* in_sizes, int n_in,
                              void* d_out, int out_size, void* d_ws, size_t ws_size,
                              hipStream_t stream) {
    const float* x  = (const float*)d_in[0];
    const int*   ei = (const int*)d_in[1];
    const float* W  = (const float*)d_in[2];
    const float* b  = (const float*)d_in[3];
    float* out = (float*)d_out;

    // ws layout (4B-unit offsets):
    // h8 [0..3.2M) | rscale 3.3M | combo 3.45M | bcur 4.13M |
    // Wimg 4.14M (34.8KB) | ebuf [4.3M .. 4.3M+782*2432=6.20M)
    signed char* h8 = (signed char*)d_ws;
    float* rscale = (float*)d_ws + 3300000;
    float* combo  = (float*)d_ws + 3450000;
    int*   bcur   = (int*)d_ws + 4130000;
    u16*   Wimg   = (u16*)((int*)d_ws + 4140000);
    unsigned int* ebuf = (unsigned int*)d_ws + 4300000;

    prep_kernel<<<16, 256, 0, stream>>>(W, Wimg, bcur);
    fused1_kernel<<<NCHUNK + GEMM_BLOCKS, 256, 0, stream>>>(x, Wimg, h8, rscale,
                                                            ei, bcur, ebuf);
    comboK_kernel<<<NBUCK, 256, 0, stream>>>(ebuf, bcur, rscale, combo);
    aggB_kernel<<<NBUCK * 2, 256, 0, stream>>>(ebuf, bcur, rscale, combo, h8, b, out);
}